// Round 3
// baseline (724.043 us; speedup 1.0000x reference)
//
#include <hip/hip_runtime.h>
#include <stdint.h>

typedef __attribute__((ext_vector_type(8))) __bf16 bf16x8;
typedef __attribute__((ext_vector_type(4))) float  f32x4;

// ---------- helpers ----------
__device__ __forceinline__ uint16_t f2b(float f) {           // fp32 -> bf16 RNE
  uint32_t u = __float_as_uint(f);
  u += 0x7fffu + ((u >> 16) & 1u);
  return (uint16_t)(u >> 16);
}
__device__ __forceinline__ float b2f_lo(uint32_t p) { return __uint_as_float(p << 16); }
__device__ __forceinline__ float b2f_hi(uint32_t p) { return __uint_as_float(p & 0xffff0000u); }

// branch-free tanh: 1 - 2/(e^{2x}+1); saturates correctly at +-1
__device__ __forceinline__ float tanh_fast(float x) {
  float e = __expf(2.0f * x);
  return 1.0f - 2.0f / (e + 1.0f);
}

__device__ __forceinline__ void bar() { asm volatile("s_barrier" ::: "memory"); }
__device__ __forceinline__ void cfence() { asm volatile("" ::: "memory"); }  // compile-order pin

// async 16B global -> LDS (DMA). LDS dest = wave-uniform base + lane*16.
__device__ __forceinline__ void gload16(const void* g, void* l) {
  __builtin_amdgcn_global_load_lds(
      (__attribute__((address_space(1))) uint32_t*)g,
      (__attribute__((address_space(3))) uint32_t*)l, 16, 0, 0);
}

// ---------- 1. encoder fp32 -> bf16 (8 elems/thread) ----------
__global__ __launch_bounds__(256) void convert_enc(const float4* __restrict__ in,
                                                   uint4* __restrict__ out) {
  int i = blockIdx.x * 256 + threadIdx.x;
  float4 a = in[2 * i], b = in[2 * i + 1];
  uint4 o;
  o.x = (uint32_t)f2b(a.x) | ((uint32_t)f2b(a.y) << 16);
  o.y = (uint32_t)f2b(a.z) | ((uint32_t)f2b(a.w) << 16);
  o.z = (uint32_t)f2b(b.x) | ((uint32_t)f2b(b.y) << 16);
  o.w = (uint32_t)f2b(b.z) | ((uint32_t)f2b(b.w) << 16);
  out[i] = o;
}

// ---------- 2. W_a (K x N) -> WT bf16 (N x K), LDS-tiled transpose ----------
__global__ __launch_bounds__(256) void convert_WT(const float* __restrict__ W,
                                                  uint16_t* __restrict__ WT) {
  __shared__ float tile[64][65];
  int k0 = (blockIdx.x & 15) * 64;
  int n0 = (blockIdx.x >> 4) * 64;
  #pragma unroll
  for (int it = 0; it < 16; ++it) {
    int idx = it * 256 + threadIdx.x;
    int kr = idx >> 6, nc = idx & 63;
    tile[kr][nc] = W[(size_t)(k0 + kr) * 1024 + n0 + nc];
  }
  __syncthreads();
  #pragma unroll
  for (int it = 0; it < 16; ++it) {
    int idx = it * 256 + threadIdx.x;
    int nr = idx >> 6, kc = idx & 63;
    WT[(size_t)(n0 + nr) * 1024 + k0 + kc] = f2b(tile[kc][nr]);
  }
}

// ---------- 3. u[b,f] += sum_{d in seg} dec_last[b,d] * U[d,f]  (fp32, atomic) ----
__global__ __launch_bounds__(256) void compute_u(const float* __restrict__ dec,
                                                 const float4* __restrict__ U4,
                                                 float* __restrict__ u) {
  int b = blockIdx.x >> 3, dseg = blockIdx.x & 7;
  __shared__ float sdec[128];
  if (threadIdx.x < 128)
    sdec[threadIdx.x] = dec[(size_t)b * 64 * 1024 + 63 * 1024 + dseg * 128 + threadIdx.x];
  __syncthreads();
  float4 a = {0.f, 0.f, 0.f, 0.f};
  const float4* Ub = U4 + (size_t)dseg * 128 * 256 + threadIdx.x;
  #pragma unroll 4
  for (int d = 0; d < 128; ++d) {
    float4 w = Ub[(size_t)d * 256];
    float s = sdec[d];
    a.x = fmaf(s, w.x, a.x);
    a.y = fmaf(s, w.y, a.y);
    a.z = fmaf(s, w.z, a.z);
    a.w = fmaf(s, w.w, a.w);
  }
  float* up = u + b * 1024 + threadIdx.x * 4;
  atomicAdd(up + 0, a.x);
  atomicAdd(up + 1, a.y);
  atomicAdd(up + 2, a.z);
  atomicAdd(up + 3, a.w);
}

// ---------- 4. fused GEMM: 128x128 tile, 4 waves, A-in-LDS + B-direct-from-L2 ----
// spart[ntile][row] = sum_{f in ntile's 128 cols} v[f]*tanh((A@W)[row,f]+u[b,f])
//
// Rationale (R2 post-mortem): 256²/8-wave was LDS-read-bound (MFMA:LDS ~ 1:3).
// Here B (WT, 2 MB, L2-resident per XCD) is loaded straight to registers
// (double-buffered, prefetched one K-step ahead; MFMA hides the L2 latency),
// so LDS carries only A: per K-step(64) per block: 16 KB staged + 32 KB read
// (vs 128 KB before). LDS 2x16KB -> with ~190 VGPR this gives 2 blocks/CU,
// restoring cross-block TLP (the m114/m97 hiding mechanism).
// vmcnt discipline: A-stage (4 gload_lds) issued FIRST each step (cfence pins
// order), B-prefetch (8 loads) after; trailing vmcnt(8) drains exactly the
// next A-tile, B stays in flight (its consumers are data-dep -> compiler
// inserts precise waits). One barrier per K-step.
// LDS swizzle: slot(r,c)=r*8+(c^(r&7)) [16B units]; staging pre-applies the
// inverse on the global source (lane-linear dest, m104 rule); frag reads land
// uniform across bank groups -> 0 conflicts (same family as R1/R2, measured 0).
__global__ __launch_bounds__(256, 2) void gemm_score(const uint16_t* __restrict__ A,
                                                     const uint16_t* __restrict__ BT,
                                                     const float* __restrict__ u,
                                                     const float* __restrict__ v,
                                                     float* __restrict__ spart) {
  __shared__ uint4 sA[2][1024];   // [dbuf][128 rows x 8 chunks of 16B]
  __shared__ float sred[128];

  // XCD-bijective swizzle (nwg=4096, %8==0). Within an XCD consecutive wg
  // share mtile across ntiles -> A-tile L2-resident, 8x reuse.
  const int bx = blockIdx.x;
  const int wgl = (bx & 7) * 512 + (bx >> 3);
  const int mtile = wgl >> 3;   // 0..511
  const int ntile = wgl & 7;    // 0..7

  const int tid = threadIdx.x;
  const int lane = tid & 63;
  const int wid = tid >> 6;            // 0..3
  const int wm = (wid >> 1) * 64;      // row half
  const int wn = (wid & 1) * 64;       // col half
  const int nib = lane & 15;
  const int q4 = lane >> 4;

  const int rowA = mtile * 128;
  const char* baseA = (const char*)A + (size_t)rowA * 2048;
  // staging: dest slot = s*256+tid (lane-linear); r = slot>>3, c' = slot&7
  // holds global chunk c = c'^(r&7); (r&7) == ((tid>>3)&7) for all sweeps.
  const size_t srcoff = (size_t)(tid >> 3) * 2048 +
                        ((size_t)((tid & 7) ^ ((tid >> 3) & 7)) << 4);
  // per-lane B pointer: col = ntile*128 + wn + nib (row of WT), k-chunk q4
  const char* pB = (const char*)BT + (size_t)(ntile * 128 + wn + nib) * 2048 + q4 * 16;

  f32x4 acc[4][4];
  #pragma unroll
  for (int i = 0; i < 4; ++i)
    #pragma unroll
    for (int j = 0; j < 4; ++j) acc[i][j] = (f32x4){0.f, 0.f, 0.f, 0.f};

  bf16x8 Bn0[4][2], Bn1[4][2];   // two named B-register sets (no runtime idx)

#define ASTAGE(buf, koff)                                                     \
  do {                                                                        \
    _Pragma("unroll")                                                         \
    for (int s = 0; s < 4; ++s)                                               \
      gload16(baseA + (koff) + s * 65536 + srcoff,                            \
              &sA[buf][s * 256 + wid * 64]);                                  \
  } while (0)

#define BLOAD(dst, koff)                                                      \
  do {                                                                        \
    _Pragma("unroll")                                                         \
    for (int j = 0; j < 4; ++j)                                               \
      _Pragma("unroll")                                                       \
      for (int kk = 0; kk < 2; ++kk)                                          \
        dst[j][kk] = *(const bf16x8*)(pB + (koff) + j * 32768 + kk * 64);     \
  } while (0)

  // prologue: stage A(0) (issued first), prefetch B(0); drain A only.
  ASTAGE(0, 0);
  cfence();
  BLOAD(Bn0, 0);
  asm volatile("s_waitcnt vmcnt(8)" ::: "memory");
  bar();

  // Steady-state step t (buffer P=t&1): issue A(t+1) -> buf P^1; ds_read
  // A-frags(t); issue B(t+1); 32 MFMA (Bcur + af); vmcnt(8) drains A(t+1);
  // barrier. Entry invariant: 8 B(t) loads in flight, A(t) landed.
#define STEP(P, Bcur, Bnxt, t, STG)                                           \
  do {                                                                        \
    if (STG) ASTAGE(P ^ 1, ((t) + 1) * 128);                                  \
    cfence();                                                                 \
    bf16x8 af[4][2];                                                          \
    _Pragma("unroll")                                                         \
    for (int mi = 0; mi < 4; ++mi)                                            \
      _Pragma("unroll")                                                       \
      for (int kk = 0; kk < 2; ++kk)                                          \
        af[mi][kk] = *(const bf16x8*)&sA[P][(wm + mi * 16 + nib) * 8 +        \
                                           (((kk << 2) + q4) ^ (nib & 7))];   \
    if (STG) BLOAD(Bnxt, ((t) + 1) * 128);                                    \
    __builtin_amdgcn_s_setprio(1);                                            \
    _Pragma("unroll")                                                         \
    for (int mi = 0; mi < 4; ++mi)                                            \
      _Pragma("unroll")                                                       \
      for (int nj = 0; nj < 4; ++nj)                                          \
        _Pragma("unroll")                                                     \
        for (int kk = 0; kk < 2; ++kk)                                        \
          acc[mi][nj] = __builtin_amdgcn_mfma_f32_16x16x32_bf16(              \
              af[mi][kk], Bcur[nj][kk], acc[mi][nj], 0, 0, 0);                \
    __builtin_amdgcn_s_setprio(0);                                            \
    if (STG) asm volatile("s_waitcnt vmcnt(8)" ::: "memory");                 \
    bar();                                                                    \
  } while (0)

  #pragma unroll
  for (int tt = 0; tt < 8; ++tt) {
    STEP(0, Bn0, Bn1, 2 * tt, true);
    STEP(1, Bn1, Bn0, 2 * tt + 1, (tt < 7));
  }
#undef STEP
#undef BLOAD
#undef ASTAGE

  // ---- epilogue: v-weighted tanh row reduction -> spart[ntile][row] ----
  const int b = mtile >> 4;  // 2048 rows per batch, 128-row block is uniform
  float vv[4], uu[4];
  #pragma unroll
  for (int j = 0; j < 4; ++j) {
    int col = ntile * 128 + wn + j * 16 + nib;
    vv[j] = v[col];
    uu[j] = u[b * 1024 + col];
  }
  float sloc[4][4];
  #pragma unroll
  for (int mi = 0; mi < 4; ++mi)
    #pragma unroll
    for (int reg = 0; reg < 4; ++reg) {
      float s = 0.f;
      #pragma unroll
      for (int j = 0; j < 4; ++j) s += vv[j] * tanh_fast(acc[mi][j][reg] + uu[j]);
      s += __shfl_xor(s, 1);
      s += __shfl_xor(s, 2);
      s += __shfl_xor(s, 4);
      s += __shfl_xor(s, 8);
      sloc[mi][reg] = s;  // row = wm + mi*16 + q4*4 + reg, cols wn..wn+63
    }
  if ((wid & 1) == 0 && nib == 0) {  // col-half 0 deposits
    #pragma unroll
    for (int mi = 0; mi < 4; ++mi)
      #pragma unroll
      for (int reg = 0; reg < 4; ++reg)
        sred[wm + mi * 16 + q4 * 4 + reg] = sloc[mi][reg];
  }
  __syncthreads();
  if ((wid & 1) == 1 && nib == 0) {  // col-half 1 combines + stores
    float* outp = spart + (size_t)ntile * 65536 + rowA;
    #pragma unroll
    for (int mi = 0; mi < 4; ++mi) {
      int r = wm + mi * 16 + q4 * 4;
      float4 sv;
      #pragma unroll
      for (int reg = 0; reg < 4; ++reg)
        ((float*)&sv)[reg] = sloc[mi][reg] + sred[r + reg];
      *(float4*)(outp + r) = sv;
    }
  }
}

// ---------- 5. softmax over t (2048) per batch; sums the 8 ntile partials ------
__global__ __launch_bounds__(256) void softmax_k(const float* __restrict__ spart,
                                                 float* __restrict__ wout) {
  int b = blockIdx.x, tid = threadIdx.x;
  __shared__ float red[4];
  float sv[8];
  float mx = -1e30f;
  #pragma unroll
  for (int i = 0; i < 8; ++i) {
    int idx = b * 2048 + i * 256 + tid;
    float s = 0.f;
    #pragma unroll
    for (int j = 0; j < 8; ++j) s += spart[j * 65536 + idx];
    sv[i] = s;
    mx = fmaxf(mx, s);
  }
  #pragma unroll
  for (int off = 1; off < 64; off <<= 1) mx = fmaxf(mx, __shfl_xor(mx, off));
  if ((tid & 63) == 0) red[tid >> 6] = mx;
  __syncthreads();
  mx = fmaxf(fmaxf(red[0], red[1]), fmaxf(red[2], red[3]));
  __syncthreads();
  float sum = 0.f;
  #pragma unroll
  for (int i = 0; i < 8; ++i) {
    sv[i] = __expf(sv[i] - mx);
    sum += sv[i];
  }
  #pragma unroll
  for (int off = 1; off < 64; off <<= 1) sum += __shfl_xor(sum, off);
  if ((tid & 63) == 0) red[tid >> 6] = sum;
  __syncthreads();
  float inv = 1.0f / (red[0] + red[1] + red[2] + red[3]);
  #pragma unroll
  for (int i = 0; i < 8; ++i) wout[b * 2048 + i * 256 + tid] = sv[i] * inv;
}

// ---------- 6a. context partials (NO atomics): per (b, 128-t chunk) ----------
__global__ __launch_bounds__(256) void context_part(const uint16_t* __restrict__ encA,
                                                    const float* __restrict__ w,
                                                    float* __restrict__ cpart) {
  int b = blockIdx.x >> 4, ch = blockIdx.x & 15;
  int t0 = ch * 128;
  __shared__ float lw[128];
  __shared__ float sctx[1024];
  if (threadIdx.x < 128) lw[threadIdx.x] = w[b * 2048 + t0 + threadIdx.x];
  __syncthreads();
  int th = threadIdx.x >> 7;   // t-half
  int i  = threadIdx.x & 127;  // elem group (8 elems)
  int e0 = i * 8;
  float a[8] = {0.f, 0.f, 0.f, 0.f, 0.f, 0.f, 0.f, 0.f};
  const uint16_t* base = encA + (size_t)b * 2048 * 1024 + (size_t)(t0 + th * 64) * 1024 + e0;
  const float* lwp = lw + th * 64;
  #pragma unroll 2
  for (int t = 0; t < 64; ++t) {
    uint4 p = *(const uint4*)(base + (size_t)t * 1024);
    float wt = lwp[t];
    a[0] = fmaf(wt, b2f_lo(p.x), a[0]);
    a[1] = fmaf(wt, b2f_hi(p.x), a[1]);
    a[2] = fmaf(wt, b2f_lo(p.y), a[2]);
    a[3] = fmaf(wt, b2f_hi(p.y), a[3]);
    a[4] = fmaf(wt, b2f_lo(p.z), a[4]);
    a[5] = fmaf(wt, b2f_hi(p.z), a[5]);
    a[6] = fmaf(wt, b2f_lo(p.w), a[6]);
    a[7] = fmaf(wt, b2f_hi(p.w), a[7]);
  }
  if (th == 0) {
    #pragma unroll
    for (int k = 0; k < 8; ++k) sctx[e0 + k] = a[k];
  }
  __syncthreads();
  if (th == 1) {
    float* cp = cpart + (size_t)(b * 16 + ch) * 1024 + e0;
    float4 v0, v1;
    #pragma unroll
    for (int k = 0; k < 4; ++k) ((float*)&v0)[k] = a[k] + sctx[e0 + k];
    #pragma unroll
    for (int k = 0; k < 4; ++k) ((float*)&v1)[k] = a[4 + k] + sctx[e0 + 4 + k];
    *(float4*)(cp) = v0;
    *(float4*)(cp + 4) = v1;
  }
}

// ---------- 6b. reduce 16 chunk-partials -> ctx (plain stores) ----------
__global__ __launch_bounds__(256) void ctx_reduce(const float* __restrict__ cpart,
                                                  float* __restrict__ ctx) {
  int idx = blockIdx.x * 256 + threadIdx.x;  // 32*1024 outputs
  int b = idx >> 10, e = idx & 1023;
  float s = 0.f;
  #pragma unroll
  for (int r = 0; r < 16; ++r) s += cpart[(size_t)(b * 16 + r) * 1024 + e];
  ctx[idx] = s;
}

extern "C" void kernel_launch(void* const* d_in, const int* in_sizes, int n_in,
                              void* d_out, int out_size, void* d_ws, size_t ws_size,
                              hipStream_t stream) {
  const float* enc = (const float*)d_in[0];  // (32, 2048, 1024)
  const float* dec = (const float*)d_in[1];  // (32, 64, 1024)
  const float* Wa  = (const float*)d_in[2];  // (1024, 1024)
  const float* Ua  = (const float*)d_in[3];  // (1024, 1024)
  const float* Va  = (const float*)d_in[4];  // (1024, 1)

  float* out = (float*)d_out;
  float* ctx = out;                 // 32*1024
  float* wts = out + 32 * 1024;     // 32*2048*1

  char* ws = (char*)d_ws;
  uint16_t* encA  = (uint16_t*)ws;                           // 128 MB bf16 encoder
  uint16_t* WT    = (uint16_t*)(ws + 134217728);             // 2 MB bf16 W^T
  float*    ub    = (float*)  (ws + 136314880);              // 128 KB u[b,f]
  float*    spart = (float*)  (ws + 136445952);              // 2 MB score partials [8][65536]
  float*    cpart = spart;  // context partials [512][1024] reuse spart (dead after softmax)

  hipMemsetAsync(ub, 0, 32 * 1024 * sizeof(float), stream);

  convert_enc<<<32768, 256, 0, stream>>>((const float4*)enc, (uint4*)encA);
  convert_WT<<<256, 256, 0, stream>>>(Wa, WT);
  compute_u<<<256, 256, 0, stream>>>(dec, (const float4*)Ua, ub);
  gemm_score<<<4096, 256, 0, stream>>>(encA, WT, ub, Va, spart);
  softmax_k<<<32, 256, 0, stream>>>(spart, wts);
  context_part<<<512, 256, 0, stream>>>(encA, wts, cpart);
  ctx_reduce<<<128, 256, 0, stream>>>(cpart, ctx);
}